// Round 9
// baseline (1303.967 us; speedup 1.0000x reference)
//
#include <hip/hip_runtime.h>
#include <math.h>

typedef float f32x2 __attribute__((ext_vector_type(2)));

#define NPTS 32768          // b*h*w*d = 1*32*32*32
#define NE   2048
#define ED   16
#define WAVES 16
#define CHUNK (NE / WAVES)   // 128
#define TILE  32             // codewords staged in LDS per refill (2 KB)
#define NT    (CHUNK / TILE) // 4 tiles per pass

// exp2-domain temperature constants (exp(x*T) == exp2(x*T*log2e))
#define KT2 20.60992915555662f          // (1/0.07) * log2(e)
#define KE2 144.26950408889634f         // 100 * log2(e)
#define LN2 0.69314718055994531f

// output layout (floats, concatenated in return order)
#define OFF_SOFT 0
#define OFF_LOSS 524288
#define OFF_HARD 524289
#define OFF_IDX  1048577

// workspace layout (floats)
#define WS_EMB  0        // 2048*16 normalized embedding
#define WS_PSUM 32768    // 2048 column sums of ent-probs
#define WS_SSUM 34816    // 1 scalar

__device__ __forceinline__ float fexp2(float x) {
#if __has_builtin(__builtin_amdgcn_exp2f)
    return __builtin_amdgcn_exp2f(x);   // v_exp_f32
#else
    float r; asm("v_exp_f32 %0, %1" : "=v"(r) : "v"(x)); return r;
#endif
}

// dot over 16 channels with v_pk_fma_f32; accumulator partition identical to
// the scalar l0..l3 version (a.x=l0 a.y=l1 b.x=l2 b.y=l3, final (l0+l1)+(l2+l3))
// -> bit-identical logits vs rounds 3/8 (argmax unchanged).
__device__ __forceinline__ float dot16(const f32x2 zn2[8], const f32x2 e[8]) {
    f32x2 a = zn2[0] * e[0];
    f32x2 b = zn2[1] * e[1];
    a = __builtin_elementwise_fma(zn2[2], e[2], a);
    b = __builtin_elementwise_fma(zn2[3], e[3], b);
    a = __builtin_elementwise_fma(zn2[4], e[4], a);
    b = __builtin_elementwise_fma(zn2[5], e[5], b);
    a = __builtin_elementwise_fma(zn2[6], e[6], a);
    b = __builtin_elementwise_fma(zn2[7], e[7], b);
    return (a.x + a.y) + (b.x + b.y);
}

__global__ __launch_bounds__(256) void vq_prep(const float* __restrict__ emb,
                                               float* __restrict__ ws) {
    int t = blockIdx.x * 256 + threadIdx.x;
    if (t < NE) {
        float v[ED]; float s = 0.f;
        #pragma unroll
        for (int c = 0; c < ED; ++c) { v[c] = emb[t * ED + c]; s += v[c] * v[c]; }
        float inv = 1.0f / fmaxf(sqrtf(s), 1e-12f);
        #pragma unroll
        for (int c = 0; c < ED; ++c) ws[WS_EMB + t * ED + c] = v[c] * inv;
        ws[WS_PSUM + t] = 0.f;
    }
    if (t == 0) ws[WS_SSUM] = 0.f;
}

__global__ __launch_bounds__(1024, 8) void vq_main(const float* __restrict__ z,
                                                   const float* __restrict__ embN,
                                                   float* __restrict__ psum,
                                                   float* __restrict__ ssum,
                                                   float* __restrict__ out) {
    const int lane = threadIdx.x & 63;
    const int w    = threadIdx.x >> 6;
    const int n    = blockIdx.x * 64 + lane;

    // LDS budget: 32768 (ecache) + 5*4096 (sm/ss1/sam/sst/sr) + 17408 (svec)
    //           = 70656 B  ->  2 blocks/CU co-resident (141312 <= 163840)
    __shared__ float4 ecache[WAVES][TILE * ED / 4];   // per-wave private tile
    __shared__ float sm [WAVES][64];
    __shared__ float ss1[WAVES][64];
    __shared__ int   sam[WAVES][64];
    __shared__ float sst[WAVES][64];
    __shared__ float sr [WAVES][64];
    __shared__ float svec[4][64][ED + 1];             // 4-buffer combine tree

    // ---- load z row (channel-strided) and l2-normalize (bit-identical to r8)
    float zn[ED]; float s = 0.f;
    #pragma unroll
    for (int c = 0; c < ED; ++c) { float v = z[c * NPTS + n]; zn[c] = v; s += v * v; }
    float rinv = 1.0f / fmaxf(sqrtf(s), 1e-12f);
    f32x2 zn2[8];
    #pragma unroll
    for (int q = 0; q < 8; ++q) zn2[q] = f32x2{zn[2 * q] * rinv, zn[2 * q + 1] * rinv};

    const int kbase = w * CHUNK;
    const float4* __restrict__ E4 = (const float4*)embN;  // 4 float4 per codeword
    float4* const wc = &ecache[w][0];
    const f32x2* const ec = (const f32x2*)wc;

    // ---- pass 1: single ascending-k online max/argmax/S1, LDS-staged tiles
    float m0 = -2.f, s10 = 0.f;               // cosines in [-1,1]
    int am0 = kbase;
    {
        // prefetch tile 0 into registers (coalesced vector loads)
        float4 v0 = E4[(size_t)kbase * 4 + lane];
        float4 v1 = E4[(size_t)kbase * 4 + 64 + lane];
        for (int t = 0; t < NT; ++t) {
            wc[lane] = v0; wc[lane + 64] = v1;        // write tile t (wave-private)
            if (t + 1 < NT) {                         // issue-early: tile t+1 in flight
                v0 = E4[(size_t)(kbase + (t + 1) * TILE) * 4 + lane];
                v1 = E4[(size_t)(kbase + (t + 1) * TILE) * 4 + 64 + lane];
            }
            for (int i = 0; i < TILE; ++i) {
                f32x2 er[8];
                #pragma unroll
                for (int q = 0; q < 8; ++q) er[q] = ec[i * 8 + q];  // broadcast reads
                float l  = dot16(zn2, er);
                float e0 = fexp2(-fabsf(l - m0) * KE2);
                bool  g  = l > m0;                    // strict >: first max kept
                am0 = g ? (kbase + t * TILE + i) : am0;
                m0  = fmaxf(m0, l);
                s10 = g ? fmaf(s10, e0, 1.0f) : (s10 + e0);
            }
        }
    }
    sm[w][lane] = m0; ss1[w][lane] = s10; sam[w][lane] = am0;
    __syncthreads();

    // ---- flash-combine the 16 wave-chunks (every thread, own row)
    float M = sm[0][lane]; int AM = sam[0][lane];
    #pragma unroll
    for (int j = 1; j < WAVES; ++j) {
        float mj = sm[j][lane];
        if (mj > M) { M = mj; AM = sam[j][lane]; }    // ascending k: > keeps first
    }
    float S1t = 0.f;
    #pragma unroll
    for (int j = 0; j < WAVES; ++j)
        S1t += ss1[j][lane] * fexp2((sm[j][lane] - M) * KE2);
    float invS1 = 1.0f / S1t;

    // ---- pass 2: z_q_soft partials, tau-sum, entropy dot, avg_probs columns
    f32x2 vec2[8];
    #pragma unroll
    for (int q = 0; q < 8; ++q) vec2[q] = f32x2{0.f, 0.f};
    float St = 0.f, r = 0.f;
    {
        float4 v0 = E4[(size_t)kbase * 4 + lane];
        float4 v1 = E4[(size_t)kbase * 4 + 64 + lane];
        for (int t = 0; t < NT; ++t) {
            wc[lane] = v0; wc[lane + 64] = v1;
            if (t + 1 < NT) {
                v0 = E4[(size_t)(kbase + (t + 1) * TILE) * 4 + lane];
                v1 = E4[(size_t)(kbase + (t + 1) * TILE) * 4 + 64 + lane];
            }
            for (int i = 0; i < TILE; i += 4) {
                float pv[4];
                #pragma unroll
                for (int j = 0; j < 4; ++j) {
                    f32x2 er[8];
                    #pragma unroll
                    for (int q = 0; q < 8; ++q) er[q] = ec[(i + j) * 8 + q];
                    float l  = dot16(zn2, er);
                    float aa = l - M;                 // <= 0, same dot order as pass 1
                    float aK = aa * KE2;
                    float rt = fexp2(aa * KT2);       // tau weight (unnormalized)
                    St += rt;
                    float p  = fexp2(aK) * invS1;     // normalized ent prob
                    r = fmaf(p, aK, r);               // Σ p·a·100·log2e
                    f32x2 rt2 = {rt, rt};
                    #pragma unroll
                    for (int q = 0; q < 8; ++q)
                        vec2[q] = __builtin_elementwise_fma(rt2, er[q], vec2[q]);
                    pv[j] = p;
                }
                // reduce pv[0..3] across 64 lanes (identical to r8)
                bool u2 = (lane & 2) != 0, u1 = (lane & 1) != 0;
                float t0 = (u2 ? pv[2] : pv[0]) + __shfl_xor(u2 ? pv[0] : pv[2], 2, 64);
                float t1 = (u2 ? pv[3] : pv[1]) + __shfl_xor(u2 ? pv[1] : pv[3], 2, 64);
                float v  = (u1 ? t1 : t0) + __shfl_xor(u1 ? t0 : t1, 1, 64);
                v += __shfl_xor(v, 4, 64);
                v += __shfl_xor(v, 8, 64);
                v += __shfl_xor(v, 16, 64);
                v += __shfl_xor(v, 32, 64);
                if (lane < 4) atomicAdd(&psum[kbase + t * TILE + i + lane], v);
            }
        }
    }

    sst[w][lane] = St; sr[w][lane] = r;
    // ---- svec 4-buffer tree: svec[j] = vec(j+4)+vec(j+8)+vec(j+12) (+vec(j), j>=1)
    if (w >= 12) {
        #pragma unroll
        for (int q = 0; q < 8; ++q) {
            svec[w - 12][lane][2 * q]     = vec2[q].x;
            svec[w - 12][lane][2 * q + 1] = vec2[q].y;
        }
    }
    __syncthreads();
    if (w >= 8 && w < 12) {
        #pragma unroll
        for (int q = 0; q < 8; ++q) {
            svec[w - 8][lane][2 * q]     += vec2[q].x;
            svec[w - 8][lane][2 * q + 1] += vec2[q].y;
        }
    }
    __syncthreads();
    if (w >= 4 && w < 8) {
        #pragma unroll
        for (int q = 0; q < 8; ++q) {
            svec[w - 4][lane][2 * q]     += vec2[q].x;
            svec[w - 4][lane][2 * q + 1] += vec2[q].y;
        }
    }
    __syncthreads();
    if (w >= 1 && w < 4) {
        #pragma unroll
        for (int q = 0; q < 8; ++q) {
            svec[w][lane][2 * q]     += vec2[q].x;
            svec[w][lane][2 * q + 1] += vec2[q].y;
        }
    }
    __syncthreads();

    // ---- epilogue (wave 0): combine + write outputs + sample-entropy
    if (w == 0) {
        float Stt = 0.f;
        #pragma unroll
        for (int j = 0; j < WAVES; ++j) Stt += sst[j][lane];
        float invSt = 1.0f / Stt;
        #pragma unroll
        for (int c = 0; c < ED; ++c) {
            float v = ((c & 1) ? vec2[c >> 1].y : vec2[c >> 1].x)
                    + svec[0][lane][c] + svec[1][lane][c]
                    + svec[2][lane][c] + svec[3][lane][c];
            out[OFF_SOFT + c * NPTS + n] = v * invSt;
        }
        out[OFF_IDX + n] = (float)AM;
        #pragma unroll
        for (int c = 0; c < ED; ++c)
            out[OFF_HARD + c * NPTS + n] = embN[AM * ED + c];
        // per-row sample term = ln(S1) - ln2 * Σ p·aK
        float rr = 0.f;
        #pragma unroll
        for (int j = 0; j < WAVES; ++j) rr += sr[j][lane];
        float row = logf(S1t) - LN2 * rr;
        #pragma unroll
        for (int off = 32; off > 0; off >>= 1) row += __shfl_xor(row, off, 64);
        if (lane == 0) atomicAdd(ssum, row);
    }
}

__global__ __launch_bounds__(256) void vq_finalize(const float* __restrict__ ws,
                                                   float* __restrict__ out) {
    __shared__ float red[4];
    float a = 0.f;
    for (int k = threadIdx.x; k < NE; k += 256) {
        float avg = ws[WS_PSUM + k] * (1.0f / 32768.0f);
        a += avg * logf(avg + 1e-6f);                 // = -avg_entropy contribution
    }
    #pragma unroll
    for (int off = 32; off > 0; off >>= 1) a += __shfl_xor(a, off, 64);
    if ((threadIdx.x & 63) == 0) red[threadIdx.x >> 6] = a;
    __syncthreads();
    if (threadIdx.x == 0) {
        float A = red[0] + red[1] + red[2] + red[3];  // A = -avg_entropy
        float sample = ws[WS_SSUM] * (1.0f / 32768.0f);
        out[OFF_LOSS] = 0.01f * (sample + A);         // ratio * (sample_ent - avg_ent)
    }
}

extern "C" void kernel_launch(void* const* d_in, const int* in_sizes, int n_in,
                              void* d_out, int out_size, void* d_ws, size_t ws_size,
                              hipStream_t stream) {
    const float* z   = (const float*)d_in[0];
    const float* emb = (const float*)d_in[1];
    float* out = (float*)d_out;
    float* ws  = (float*)d_ws;   // needs 34817 floats (~136 KB)

    vq_prep<<<(NE + 255) / 256, 256, 0, stream>>>(emb, ws);
    vq_main<<<NPTS / 64, WAVES * 64, 0, stream>>>(z, ws + WS_EMB, ws + WS_PSUM,
                                                  ws + WS_SSUM, out);
    vq_finalize<<<1, 256, 0, stream>>>(ws, out);
}